// Round 1
// baseline (1187.811 us; speedup 1.0000x reference)
//
#include <hip/hip_runtime.h>
#include <cstdio>
#include <cstdint>
#include <cstddef>

// Problem constants (B=4, S=2048, D=1024, F=2048, E=8, K=2, CF=1.25)
#define T_TOK 8192
#define E_N 8
#define D_M 1024
#define F_F 2048
#define A_N (T_TOK * 2)      // 16384 assignments
#define CAP 2560             // ceil(1.25 * 16384 / 8)
#define NCHUNK (A_N / 64)    // 256 chunks of 64 assignments

typedef __attribute__((ext_vector_type(4))) float floatx4;
typedef __attribute__((ext_vector_type(8))) short shortx8;

__device__ __forceinline__ unsigned short f2bf(float f) {
    union { float f; unsigned int u; } v; v.f = f;
    unsigned int u = v.u;
    u += 0x7fffu + ((u >> 16) & 1u);   // round-to-nearest-even
    return (unsigned short)(u >> 16);
}
__device__ __forceinline__ float bf2f(unsigned short h) {
    union { unsigned int u; float f; } v; v.u = ((unsigned int)h) << 16;
    return v.f;
}

// ---------------- Router: one wave per token, top-2 experts + weights ----------------
__global__ void router_kernel(const float* __restrict__ x,
                              const float* __restrict__ rw,
                              const float* __restrict__ rb,
                              int* __restrict__ tk_e,
                              float* __restrict__ tk_w) {
    int t = blockIdx.x * 4 + (threadIdx.x >> 6);
    int lane = threadIdx.x & 63;
    float acc[E_N];
#pragma unroll
    for (int e = 0; e < E_N; ++e) acc[e] = 0.f;
    const float* xr = x + (size_t)t * D_M;
    for (int d = lane; d < D_M; d += 64) {
        float xv = xr[d];
        const float* r = rw + d * E_N;
#pragma unroll
        for (int e = 0; e < E_N; ++e) acc[e] += xv * r[e];
    }
#pragma unroll
    for (int off = 32; off > 0; off >>= 1) {
#pragma unroll
        for (int e = 0; e < E_N; ++e) acc[e] += __shfl_down(acc[e], off);
    }
    if (lane == 0) {
        float la[E_N];
#pragma unroll
        for (int e = 0; e < E_N; ++e) la[e] = acc[e] + rb[e];
        int e0 = 0; float l0 = la[0];
#pragma unroll
        for (int e = 1; e < E_N; ++e) { if (la[e] > l0) { l0 = la[e]; e0 = e; } }
        int e1 = -1; float l1 = -3.0e38f;
#pragma unroll
        for (int e = 0; e < E_N; ++e) { if (e != e0 && la[e] > l1) { l1 = la[e]; e1 = e; } }
        // top2 softmax renormalized == sigmoid of logit gap
        float w0 = 1.f / (1.f + expf(l1 - l0));
        tk_e[2 * t]     = e0;
        tk_e[2 * t + 1] = e1;
        tk_w[2 * t]     = w0;
        tk_w[2 * t + 1] = 1.f - w0;
    }
}

// ---------------- Per-chunk expert histogram (chunk = 64 assignments = 1 wave) ----------------
__global__ void hist_kernel(const int* __restrict__ tk_e, int* __restrict__ hist) {
    int a = blockIdx.x * 256 + threadIdx.x;
    int lane = threadIdx.x & 63;
    int chunk = a >> 6;
    int e = tk_e[a];
#pragma unroll
    for (int ee = 0; ee < E_N; ++ee) {
        unsigned long long b = __ballot(e == ee);
        if (lane == ee) hist[chunk * E_N + ee] = (int)__popcll(b);
    }
}

// ---------------- Exclusive prefix over chunks, per expert ----------------
__global__ void scan_kernel(const int* __restrict__ hist, int* __restrict__ cpre) {
    int e = threadIdx.x;
    if (e < E_N) {
        int run = 0;
#pragma unroll 8
        for (int c = 0; c < NCHUNK; ++c) {
            cpre[c * E_N + e] = run;
            run += hist[c * E_N + e];
        }
    }
}

__global__ void init_slots_kernel(int* __restrict__ slot_token) {
    int i = blockIdx.x * 256 + threadIdx.x;
    if (i < E_N * CAP) slot_token[i] = -1;
}

// ---------------- Rank within expert (stable order), capacity drop, slot maps ----------------
__global__ void slot_kernel(const int* __restrict__ tk_e, const int* __restrict__ cpre,
                            int* __restrict__ a_slot, int* __restrict__ slot_token) {
    int a = blockIdx.x * 256 + threadIdx.x;
    int lane = threadIdx.x & 63;
    int chunk = a >> 6;
    int e = tk_e[a];
    unsigned long long mymask = 0;
#pragma unroll
    for (int ee = 0; ee < E_N; ++ee) {
        unsigned long long b = __ballot(e == ee);
        if (e == ee) mymask = b;
    }
    int rank = cpre[chunk * E_N + e] + (int)__popcll(mymask & ((1ull << lane) - 1ull));
    int slot = (rank < CAP) ? e * CAP + rank : -1;
    a_slot[a] = slot;
    if (slot >= 0) slot_token[slot] = a >> 1;
}

// ---------------- Gather tokens into [E*CAP, D] bf16 buffer (zeros for empty slots) ----------------
__global__ void dispatch_kernel(const float* __restrict__ x, const int* __restrict__ slot_token,
                                unsigned short* __restrict__ xbuf) {
    int row = blockIdx.x;
    int tok = slot_token[row];
    int c = threadIdx.x * 4;
    float4 v = {0.f, 0.f, 0.f, 0.f};
    if (tok >= 0) v = *(const float4*)(x + (size_t)tok * D_M + c);
    union { unsigned short s[4]; uint2 u; } o;
    o.s[0] = f2bf(v.x); o.s[1] = f2bf(v.y); o.s[2] = f2bf(v.z); o.s[3] = f2bf(v.w);
    *(uint2*)(xbuf + (size_t)row * D_M + c) = o.u;
}

// ---------------- Weight convert + transpose: [e][R][C] f32 -> [e][C][R] bf16 ----------------
__global__ void wconv_kernel(const float* __restrict__ in, unsigned short* __restrict__ out,
                             int R, int C) {
    __shared__ float tile[32][33];
    int e = blockIdx.z;
    int c0 = blockIdx.x * 32;
    int r0 = blockIdx.y * 32;
    const float* ine = in + (size_t)e * R * C;
    unsigned short* oute = out + (size_t)e * R * C;
    int tr = threadIdx.x >> 3;
    int tc = (threadIdx.x & 7) * 4;
    float4 v = *(const float4*)(ine + (size_t)(r0 + tr) * C + c0 + tc);
    tile[tr][tc + 0] = v.x; tile[tr][tc + 1] = v.y;
    tile[tr][tc + 2] = v.z; tile[tr][tc + 3] = v.w;
    __syncthreads();
    int oc = threadIdx.x >> 3;          // local out-row (= in col)
    int orr = (threadIdx.x & 7) * 4;    // local out-col (= in row)
    union { unsigned short s[4]; uint2 u; } o;
#pragma unroll
    for (int j = 0; j < 4; ++j) o.s[j] = f2bf(tile[orr + j][oc]);
    *(uint2*)(oute + (size_t)(c0 + oc) * R + r0 + orr) = o.u;
}

// ---------------- bf16 MFMA GEMM: C[e] = epi(A[e][M,K] @ B[e][N,K]^T + bias[e])  ----------------
// 128x128 tile, BK=64, 4 waves (2x2), each wave 64x64 via 4x4 of 16x16x32 MFMA.
// LDS layout XOR-swizzled by 16B chunk so staging writes and ds_read_b128 frag reads
// are both <=2-way bank aliasing (free on gfx950, m136).
template <int EPI>
__global__ __launch_bounds__(256) void gemm_kernel(
    const unsigned short* __restrict__ A,
    const unsigned short* __restrict__ B,
    const float* __restrict__ bias,
    unsigned short* __restrict__ C,
    int M, int N, int K) {
    __shared__ __align__(16) unsigned short As[128 * 64];
    __shared__ __align__(16) unsigned short Bs[128 * 64];
    int e = blockIdx.z;
    int m0 = blockIdx.x * 128;
    int n0 = blockIdx.y * 128;
    const unsigned short* Ae = A + (size_t)e * M * K + (size_t)m0 * K;
    const unsigned short* Be = B + (size_t)e * N * K + (size_t)n0 * K;
    int tid = threadIdx.x;
    int lane = tid & 63;
    int wave = tid >> 6;
    int wm = (wave >> 1) * 64;
    int wn = (wave & 1) * 64;
    int srow = tid >> 3;   // 0..31 staging row within 32-row group
    int skc = tid & 7;     // 16B chunk within 128B row
    int sw = (skc ^ (srow & 7)) * 8;   // swizzled chunk offset (elements)
    int l15 = lane & 15;
    int l4 = lane >> 4;

    floatx4 acc[4][4];
#pragma unroll
    for (int i = 0; i < 4; ++i)
#pragma unroll
        for (int j = 0; j < 4; ++j) acc[i][j] = (floatx4){0.f, 0.f, 0.f, 0.f};

    for (int kt = 0; kt < K; kt += 64) {
        uint4 ar[4], br[4];
#pragma unroll
        for (int p = 0; p < 4; ++p) {
            ar[p] = *(const uint4*)(Ae + (size_t)(p * 32 + srow) * K + kt + skc * 8);
            br[p] = *(const uint4*)(Be + (size_t)(p * 32 + srow) * K + kt + skc * 8);
        }
        __syncthreads();
#pragma unroll
        for (int p = 0; p < 4; ++p) {
            *(uint4*)(As + (p * 32 + srow) * 64 + sw) = ar[p];
            *(uint4*)(Bs + (p * 32 + srow) * 64 + sw) = br[p];
        }
        __syncthreads();
#pragma unroll
        for (int ks = 0; ks < 2; ++ks) {
            shortx8 af[4], bf[4];
            int kc = ks * 4 + l4;
#pragma unroll
            for (int i = 0; i < 4; ++i) {
                int m = wm + i * 16 + l15;
                af[i] = *(const shortx8*)(As + m * 64 + ((kc ^ (m & 7)) * 8));
                int n = wn + i * 16 + l15;
                bf[i] = *(const shortx8*)(Bs + n * 64 + ((kc ^ (n & 7)) * 8));
            }
#pragma unroll
            for (int i = 0; i < 4; ++i)
#pragma unroll
                for (int j = 0; j < 4; ++j)
                    acc[i][j] = __builtin_amdgcn_mfma_f32_16x16x32_bf16(af[i], bf[j], acc[i][j], 0, 0, 0);
        }
    }

    // Epilogue: C/D layout col=lane&15, row=(lane>>4)*4+reg
#pragma unroll
    for (int i = 0; i < 4; ++i) {
        int mbase = m0 + wm + i * 16 + l4 * 4;
#pragma unroll
        for (int j = 0; j < 4; ++j) {
            int n = n0 + wn + j * 16 + l15;
            float bv = bias[e * N + n];
#pragma unroll
            for (int r = 0; r < 4; ++r) {
                float v = acc[i][j][r] + bv;
                if (EPI == 0) v = 0.5f * v * (1.0f + erff(v * 0.70710678118654752f));
                C[((size_t)e * M + mbase + r) * N + n] = f2bf(v);
            }
        }
    }
}

// ---------------- Combine: out[t] = sum_k w_k * eo[slot_k] ----------------
__global__ void combine_kernel(const unsigned short* __restrict__ eo,
                               const int* __restrict__ a_slot,
                               const float* __restrict__ tk_w,
                               float* __restrict__ out) {
    int t = blockIdx.x;
    int c = threadIdx.x * 4;
    int s0 = a_slot[2 * t], s1 = a_slot[2 * t + 1];
    float w0 = tk_w[2 * t], w1 = tk_w[2 * t + 1];
    float o0 = 0.f, o1 = 0.f, o2 = 0.f, o3 = 0.f;
    if (s0 >= 0) {
        union { unsigned short s[4]; uint2 u; } v;
        v.u = *(const uint2*)(eo + (size_t)s0 * D_M + c);
        o0 += w0 * bf2f(v.s[0]); o1 += w0 * bf2f(v.s[1]);
        o2 += w0 * bf2f(v.s[2]); o3 += w0 * bf2f(v.s[3]);
    }
    if (s1 >= 0) {
        union { unsigned short s[4]; uint2 u; } v;
        v.u = *(const uint2*)(eo + (size_t)s1 * D_M + c);
        o0 += w1 * bf2f(v.s[0]); o1 += w1 * bf2f(v.s[1]);
        o2 += w1 * bf2f(v.s[2]); o3 += w1 * bf2f(v.s[3]);
    }
    float4 o = {o0, o1, o2, o3};
    *(float4*)(out + (size_t)t * D_M + c) = o;
}

extern "C" void kernel_launch(void* const* d_in, const int* in_sizes, int n_in,
                              void* d_out, int out_size, void* d_ws, size_t ws_size,
                              hipStream_t stream) {
    const float* x  = (const float*)d_in[0];
    const float* rw = (const float*)d_in[1];
    const float* rb = (const float*)d_in[2];
    const float* w1 = (const float*)d_in[3];
    const float* b1 = (const float*)d_in[4];
    const float* w2 = (const float*)d_in[5];
    const float* b2 = (const float*)d_in[6];
    float* out = (float*)d_out;

    char* ws = (char*)d_ws;
    size_t off = 0;
    auto alloc = [&](size_t bytes) -> char* {
        char* p = ws + off;
        off += (bytes + 255) & ~(size_t)255;
        return p;
    };
    unsigned short* w1t  = (unsigned short*)alloc((size_t)E_N * D_M * F_F * 2);  // [E][F][D] bf16
    unsigned short* w2t  = (unsigned short*)alloc((size_t)E_N * D_M * F_F * 2);  // [E][D][F] bf16
    unsigned short* xbuf = (unsigned short*)alloc((size_t)E_N * CAP * D_M * 2);  // [E*CAP][D] bf16
    unsigned short* h    = (unsigned short*)alloc((size_t)E_N * CAP * F_F * 2);  // [E*CAP][F] bf16
    unsigned short* eo   = (unsigned short*)alloc((size_t)E_N * CAP * D_M * 2);  // [E*CAP][D] bf16
    int*   tk_e       = (int*)alloc((size_t)A_N * 4);
    float* tk_w       = (float*)alloc((size_t)A_N * 4);
    int*   hist       = (int*)alloc((size_t)NCHUNK * E_N * 4);
    int*   cpre       = (int*)alloc((size_t)NCHUNK * E_N * 4);
    int*   a_slot     = (int*)alloc((size_t)A_N * 4);
    int*   slot_token = (int*)alloc((size_t)E_N * CAP * 4);
    if (off > ws_size) {
        fprintf(stderr, "kernel_launch: workspace too small: need %zu, have %zu\n", off, ws_size);
        return;
    }

    // weight bf16 transpose-convert (independent of routing)
    wconv_kernel<<<dim3(F_F / 32, D_M / 32, E_N), 256, 0, stream>>>(w1, w1t, D_M, F_F);
    wconv_kernel<<<dim3(D_M / 32, F_F / 32, E_N), 256, 0, stream>>>(w2, w2t, F_F, D_M);
    // routing pipeline
    router_kernel<<<T_TOK / 4, 256, 0, stream>>>(x, rw, rb, tk_e, tk_w);
    hist_kernel<<<A_N / 256, 256, 0, stream>>>(tk_e, hist);
    scan_kernel<<<1, 64, 0, stream>>>(hist, cpre);
    init_slots_kernel<<<(E_N * CAP + 255) / 256, 256, 0, stream>>>(slot_token);
    slot_kernel<<<A_N / 256, 256, 0, stream>>>(tk_e, cpre, a_slot, slot_token);
    dispatch_kernel<<<E_N * CAP, 256, 0, stream>>>(x, slot_token, xbuf);
    // expert FFN
    gemm_kernel<0><<<dim3(CAP / 128, F_F / 128, E_N), 256, 0, stream>>>(xbuf, w1t, b1, h, CAP, F_F, D_M);
    gemm_kernel<1><<<dim3(CAP / 128, D_M / 128, E_N), 256, 0, stream>>>(h, w2t, b2, eo, CAP, D_M, F_F);
    // weighted combine
    combine_kernel<<<T_TOK, 256, 0, stream>>>(eo, a_slot, tk_w, out);
}

// Round 2
// 568.260 us; speedup vs baseline: 2.0903x; 2.0903x over previous
//
#include <hip/hip_runtime.h>
#include <cstdio>
#include <cstdint>
#include <cstddef>

// Problem constants (B=4, S=2048, D=1024, F=2048, E=8, K=2, CF=1.25)
#define T_TOK 8192
#define E_N 8
#define D_M 1024
#define F_F 2048
#define A_N (T_TOK * 2)      // 16384 assignments
#define CAP 2560             // ceil(1.25 * 16384 / 8)
#define NCHUNK (A_N / 64)    // 256 chunks of 64 assignments

typedef __attribute__((ext_vector_type(4))) float floatx4;
typedef __attribute__((ext_vector_type(8))) short shortx8;

__device__ __forceinline__ unsigned short f2bf(float f) {
    union { float f; unsigned int u; } v; v.f = f;
    unsigned int u = v.u;
    u += 0x7fffu + ((u >> 16) & 1u);   // round-to-nearest-even
    return (unsigned short)(u >> 16);
}
__device__ __forceinline__ float bf2f(unsigned short h) {
    union { unsigned int u; float f; } v; v.u = ((unsigned int)h) << 16;
    return v.f;
}

// async global->LDS, 16B per lane (dest = wave-uniform base + lane*16)
__device__ __forceinline__ void async16(const unsigned short* g, unsigned short* l) {
    __builtin_amdgcn_global_load_lds(
        (const __attribute__((address_space(1))) unsigned int*)(g),
        (__attribute__((address_space(3))) unsigned int*)(l),
        16, 0, 0);
}

// ---------------- Router: one wave per token, top-2 experts + weights ----------------
__global__ void router_kernel(const float* __restrict__ x,
                              const float* __restrict__ rw,
                              const float* __restrict__ rb,
                              int* __restrict__ tk_e,
                              float* __restrict__ tk_w) {
    int t = blockIdx.x * 4 + (threadIdx.x >> 6);
    int lane = threadIdx.x & 63;
    float acc[E_N];
#pragma unroll
    for (int e = 0; e < E_N; ++e) acc[e] = 0.f;
    const float* xr = x + (size_t)t * D_M;
    for (int d = lane; d < D_M; d += 64) {
        float xv = xr[d];
        const float* r = rw + d * E_N;
#pragma unroll
        for (int e = 0; e < E_N; ++e) acc[e] += xv * r[e];
    }
#pragma unroll
    for (int off = 32; off > 0; off >>= 1) {
#pragma unroll
        for (int e = 0; e < E_N; ++e) acc[e] += __shfl_down(acc[e], off);
    }
    if (lane == 0) {
        float la[E_N];
#pragma unroll
        for (int e = 0; e < E_N; ++e) la[e] = acc[e] + rb[e];
        int e0 = 0; float l0 = la[0];
#pragma unroll
        for (int e = 1; e < E_N; ++e) { if (la[e] > l0) { l0 = la[e]; e0 = e; } }
        int e1 = -1; float l1 = -3.0e38f;
#pragma unroll
        for (int e = 0; e < E_N; ++e) { if (e != e0 && la[e] > l1) { l1 = la[e]; e1 = e; } }
        // top2 softmax renormalized == sigmoid of logit gap
        float w0 = 1.f / (1.f + expf(l1 - l0));
        tk_e[2 * t]     = e0;
        tk_e[2 * t + 1] = e1;
        tk_w[2 * t]     = w0;
        tk_w[2 * t + 1] = 1.f - w0;
    }
}

// ---------------- Per-chunk expert histogram (chunk = 64 assignments = 1 wave) ----------------
__global__ void hist_kernel(const int* __restrict__ tk_e, int* __restrict__ hist) {
    int a = blockIdx.x * 256 + threadIdx.x;
    int lane = threadIdx.x & 63;
    int chunk = a >> 6;
    int e = tk_e[a];
#pragma unroll
    for (int ee = 0; ee < E_N; ++ee) {
        unsigned long long b = __ballot(e == ee);
        if (lane == ee) hist[chunk * E_N + ee] = (int)__popcll(b);
    }
}

// ---------------- Exclusive prefix over chunks, per expert ----------------
__global__ void scan_kernel(const int* __restrict__ hist, int* __restrict__ cpre) {
    int e = threadIdx.x;
    if (e < E_N) {
        int run = 0;
#pragma unroll 8
        for (int c = 0; c < NCHUNK; ++c) {
            cpre[c * E_N + e] = run;
            run += hist[c * E_N + e];
        }
    }
}

__global__ void init_slots_kernel(int* __restrict__ slot_token) {
    int i = blockIdx.x * 256 + threadIdx.x;
    if (i < E_N * CAP) slot_token[i] = -1;
}

// ---------------- Rank within expert (stable order), capacity drop, slot maps ----------------
__global__ void slot_kernel(const int* __restrict__ tk_e, const int* __restrict__ cpre,
                            int* __restrict__ a_slot, int* __restrict__ slot_token) {
    int a = blockIdx.x * 256 + threadIdx.x;
    int lane = threadIdx.x & 63;
    int chunk = a >> 6;
    int e = tk_e[a];
    unsigned long long mymask = 0;
#pragma unroll
    for (int ee = 0; ee < E_N; ++ee) {
        unsigned long long b = __ballot(e == ee);
        if (e == ee) mymask = b;
    }
    int rank = cpre[chunk * E_N + e] + (int)__popcll(mymask & ((1ull << lane) - 1ull));
    int slot = (rank < CAP) ? e * CAP + rank : -1;
    a_slot[a] = slot;
    if (slot >= 0) slot_token[slot] = a >> 1;
}

// ---------------- Gather tokens into [E*CAP, D] bf16 buffer (zeros for empty slots) ----------------
__global__ void dispatch_kernel(const float* __restrict__ x, const int* __restrict__ slot_token,
                                unsigned short* __restrict__ xbuf) {
    int row = blockIdx.x;
    int tok = slot_token[row];
    int c = threadIdx.x * 4;
    float4 v = {0.f, 0.f, 0.f, 0.f};
    if (tok >= 0) v = *(const float4*)(x + (size_t)tok * D_M + c);
    union { unsigned short s[4]; uint2 u; } o;
    o.s[0] = f2bf(v.x); o.s[1] = f2bf(v.y); o.s[2] = f2bf(v.z); o.s[3] = f2bf(v.w);
    *(uint2*)(xbuf + (size_t)row * D_M + c) = o.u;
}

// ---------------- Weight convert + transpose: [e][R][C] f32 -> [e][C][R] bf16 ----------------
__global__ void wconv_kernel(const float* __restrict__ in, unsigned short* __restrict__ out,
                             int R, int C) {
    __shared__ float tile[32][33];
    int e = blockIdx.z;
    int c0 = blockIdx.x * 32;
    int r0 = blockIdx.y * 32;
    const float* ine = in + (size_t)e * R * C;
    unsigned short* oute = out + (size_t)e * R * C;
    int tr = threadIdx.x >> 3;
    int tc = (threadIdx.x & 7) * 4;
    float4 v = *(const float4*)(ine + (size_t)(r0 + tr) * C + c0 + tc);
    tile[tr][tc + 0] = v.x; tile[tr][tc + 1] = v.y;
    tile[tr][tc + 2] = v.z; tile[tr][tc + 3] = v.w;
    __syncthreads();
    int oc = threadIdx.x >> 3;          // local out-row (= in col)
    int orr = (threadIdx.x & 7) * 4;    // local out-col (= in row)
    union { unsigned short s[4]; uint2 u; } o;
#pragma unroll
    for (int j = 0; j < 4; ++j) o.s[j] = f2bf(tile[orr + j][oc]);
    *(uint2*)(oute + (size_t)(c0 + oc) * R + r0 + orr) = o.u;
}

// ---------------- bf16 MFMA GEMM (m97 structure): C[e] = epi(A[e][M,K] @ B[e][N,K]^T + bias[e]) ----
// 128x128 tile, BK=64, 4 waves (2x2), each wave 64x64 via 4x4 of 16x16x32 MFMA.
// global_load_lds width=16 staging into contiguous LDS (layout fixed: base + lane*16).
// MFMA operands SWAPPED (bf, af) -> D transposed: lane holds row m=lane&15,
// cols n = quad*4 + reg -> 8B packed stores (full-line friendly).
// 1D grid with XCD swizzle: e = id%8 (expert pinned to one XCD for B-in-L2 reuse),
// n-tile fastest within each m-tile (A strip reused 16x consecutively).
template <int EPI>
__global__ __launch_bounds__(256) void gemm_kernel(
    const unsigned short* __restrict__ A,
    const unsigned short* __restrict__ B,
    const float* __restrict__ bias,
    unsigned short* __restrict__ C,
    int M, int N, int K, int nt) {
    __shared__ __align__(16) unsigned short As[128 * 64];
    __shared__ __align__(16) unsigned short Bs[128 * 64];
    int id = blockIdx.x;
    int e = id & 7;
    int local = id >> 3;
    int m0 = (local / nt) * 128;
    int n0 = (local % nt) * 128;
    const unsigned short* Ae = A + (size_t)e * M * K + (size_t)m0 * K;
    const unsigned short* Be = B + (size_t)e * N * K + (size_t)n0 * K;
    int tid = threadIdx.x;
    int lane = tid & 63;
    int wave = tid >> 6;
    int wm = (wave >> 1) * 64;
    int wn = (wave & 1) * 64;
    int l15 = lane & 15;
    int l4 = lane >> 4;
    // staging: thread covers LDS elements [p*2048 + tid*8, +8) -> row p*32+tid/8, col (tid&7)*8
    int srow = tid >> 3;
    int scol = (tid & 7) * 8;

    floatx4 acc[4][4];
#pragma unroll
    for (int i = 0; i < 4; ++i)
#pragma unroll
        for (int j = 0; j < 4; ++j) acc[i][j] = (floatx4){0.f, 0.f, 0.f, 0.f};

    for (int kt = 0; kt < K; kt += 64) {
        __syncthreads();   // prior iter's LDS reads must finish before overwrite
#pragma unroll
        for (int p = 0; p < 4; ++p) {
            async16(Ae + (size_t)(p * 32 + srow) * K + kt + scol, As + p * 2048 + tid * 8);
            async16(Be + (size_t)(p * 32 + srow) * K + kt + scol, Bs + p * 2048 + tid * 8);
        }
        __syncthreads();   // drains vmcnt: staging visible
#pragma unroll
        for (int ks = 0; ks < 2; ++ks) {
            shortx8 af[4], bf[4];
            int kc = ks * 4 + l4;
#pragma unroll
            for (int i = 0; i < 4; ++i) {
                af[i] = *(const shortx8*)(As + (wm + i * 16 + l15) * 64 + kc * 8);
                bf[i] = *(const shortx8*)(Bs + (wn + i * 16 + l15) * 64 + kc * 8);
            }
#pragma unroll
            for (int i = 0; i < 4; ++i)
#pragma unroll
                for (int j = 0; j < 4; ++j)
                    acc[i][j] = __builtin_amdgcn_mfma_f32_16x16x32_bf16(bf[j], af[i], acc[i][j], 0, 0, 0);
        }
    }

    // Epilogue: swapped-operand D layout: lane row m = lane&15, cols n = l4*4 + reg
#pragma unroll
    for (int i = 0; i < 4; ++i) {
        int row = m0 + wm + i * 16 + l15;
#pragma unroll
        for (int j = 0; j < 4; ++j) {
            int ncol = n0 + wn + j * 16 + l4 * 4;
            float4 bv = *(const float4*)(bias + (size_t)e * N + ncol);
            union { unsigned short s[4]; uint2 u; } o;
#pragma unroll
            for (int r = 0; r < 4; ++r) {
                float v = acc[i][j][r] + ((const float*)&bv)[r];
                if (EPI == 0) v = 0.5f * v * (1.0f + erff(v * 0.70710678118654752f));
                o.s[r] = f2bf(v);
            }
            *(uint2*)(C + ((size_t)e * M + row) * N + ncol) = o.u;
        }
    }
}

// ---------------- Combine: out[t] = sum_k w_k * eo[slot_k] ----------------
__global__ void combine_kernel(const unsigned short* __restrict__ eo,
                               const int* __restrict__ a_slot,
                               const float* __restrict__ tk_w,
                               float* __restrict__ out) {
    int t = blockIdx.x;
    int c = threadIdx.x * 4;
    int s0 = a_slot[2 * t], s1 = a_slot[2 * t + 1];
    float w0 = tk_w[2 * t], w1 = tk_w[2 * t + 1];
    float o0 = 0.f, o1 = 0.f, o2 = 0.f, o3 = 0.f;
    if (s0 >= 0) {
        union { unsigned short s[4]; uint2 u; } v;
        v.u = *(const uint2*)(eo + (size_t)s0 * D_M + c);
        o0 += w0 * bf2f(v.s[0]); o1 += w0 * bf2f(v.s[1]);
        o2 += w0 * bf2f(v.s[2]); o3 += w0 * bf2f(v.s[3]);
    }
    if (s1 >= 0) {
        union { unsigned short s[4]; uint2 u; } v;
        v.u = *(const uint2*)(eo + (size_t)s1 * D_M + c);
        o0 += w1 * bf2f(v.s[0]); o1 += w1 * bf2f(v.s[1]);
        o2 += w1 * bf2f(v.s[2]); o3 += w1 * bf2f(v.s[3]);
    }
    float4 o = {o0, o1, o2, o3};
    *(float4*)(out + (size_t)t * D_M + c) = o;
}

extern "C" void kernel_launch(void* const* d_in, const int* in_sizes, int n_in,
                              void* d_out, int out_size, void* d_ws, size_t ws_size,
                              hipStream_t stream) {
    const float* x  = (const float*)d_in[0];
    const float* rw = (const float*)d_in[1];
    const float* rb = (const float*)d_in[2];
    const float* w1 = (const float*)d_in[3];
    const float* b1 = (const float*)d_in[4];
    const float* w2 = (const float*)d_in[5];
    const float* b2 = (const float*)d_in[6];
    float* out = (float*)d_out;

    char* ws = (char*)d_ws;
    size_t off = 0;
    auto alloc = [&](size_t bytes) -> char* {
        char* p = ws + off;
        off += (bytes + 255) & ~(size_t)255;
        return p;
    };
    unsigned short* w1t  = (unsigned short*)alloc((size_t)E_N * D_M * F_F * 2);  // [E][F][D] bf16
    unsigned short* w2t  = (unsigned short*)alloc((size_t)E_N * D_M * F_F * 2);  // [E][D][F] bf16
    unsigned short* xbuf = (unsigned short*)alloc((size_t)E_N * CAP * D_M * 2);  // [E*CAP][D] bf16
    unsigned short* h    = (unsigned short*)alloc((size_t)E_N * CAP * F_F * 2);  // [E*CAP][F] bf16
    unsigned short* eo   = (unsigned short*)alloc((size_t)E_N * CAP * D_M * 2);  // [E*CAP][D] bf16
    int*   tk_e       = (int*)alloc((size_t)A_N * 4);
    float* tk_w       = (float*)alloc((size_t)A_N * 4);
    int*   hist       = (int*)alloc((size_t)NCHUNK * E_N * 4);
    int*   cpre       = (int*)alloc((size_t)NCHUNK * E_N * 4);
    int*   a_slot     = (int*)alloc((size_t)A_N * 4);
    int*   slot_token = (int*)alloc((size_t)E_N * CAP * 4);
    if (off > ws_size) {
        fprintf(stderr, "kernel_launch: workspace too small: need %zu, have %zu\n", off, ws_size);
        return;
    }

    // weight bf16 transpose-convert (independent of routing)
    wconv_kernel<<<dim3(F_F / 32, D_M / 32, E_N), 256, 0, stream>>>(w1, w1t, D_M, F_F);
    wconv_kernel<<<dim3(D_M / 32, F_F / 32, E_N), 256, 0, stream>>>(w2, w2t, F_F, D_M);
    // routing pipeline
    router_kernel<<<T_TOK / 4, 256, 0, stream>>>(x, rw, rb, tk_e, tk_w);
    hist_kernel<<<A_N / 256, 256, 0, stream>>>(tk_e, hist);
    scan_kernel<<<1, 64, 0, stream>>>(hist, cpre);
    init_slots_kernel<<<(E_N * CAP + 255) / 256, 256, 0, stream>>>(slot_token);
    slot_kernel<<<A_N / 256, 256, 0, stream>>>(tk_e, cpre, a_slot, slot_token);
    dispatch_kernel<<<E_N * CAP, 256, 0, stream>>>(x, slot_token, xbuf);
    // expert FFN (1D grids: E * mt * nt blocks, XCD swizzle inside)
    gemm_kernel<0><<<E_N * (CAP / 128) * (F_F / 128), 256, 0, stream>>>(
        xbuf, w1t, b1, h, CAP, F_F, D_M, F_F / 128);
    gemm_kernel<1><<<E_N * (CAP / 128) * (D_M / 128), 256, 0, stream>>>(
        h, w2t, b2, eo, CAP, D_M, F_F, D_M / 128);
    // weighted combine
    combine_kernel<<<T_TOK, 256, 0, stream>>>(eo, a_slot, tk_w, out);
}

// Round 3
// 506.882 us; speedup vs baseline: 2.3434x; 1.1211x over previous
//
#include <hip/hip_runtime.h>
#include <cstdio>
#include <cstdint>
#include <cstddef>

// Problem constants (B=4, S=2048, D=1024, F=2048, E=8, K=2, CF=1.25)
#define T_TOK 8192
#define E_N 8
#define D_M 1024
#define F_F 2048
#define A_N (T_TOK * 2)      // 16384 assignments
#define CAP 2560             // ceil(1.25 * 16384 / 8)
#define NCHUNK (A_N / 64)    // 256 chunks of 64 assignments

typedef __attribute__((ext_vector_type(4))) float floatx4;
typedef __attribute__((ext_vector_type(8))) short shortx8;

__device__ __forceinline__ unsigned short f2bf(float f) {
    union { float f; unsigned int u; } v; v.f = f;
    unsigned int u = v.u;
    u += 0x7fffu + ((u >> 16) & 1u);   // round-to-nearest-even
    return (unsigned short)(u >> 16);
}
__device__ __forceinline__ float bf2f(unsigned short h) {
    union { unsigned int u; float f; } v; v.u = ((unsigned int)h) << 16;
    return v.f;
}

// async global->LDS, 16B per lane (dest = wave-uniform base + lane*16)
__device__ __forceinline__ void async16(const unsigned short* g, unsigned short* l) {
    __builtin_amdgcn_global_load_lds(
        (const __attribute__((address_space(1))) unsigned int*)(g),
        (__attribute__((address_space(3))) unsigned int*)(l),
        16, 0, 0);
}

// ---------------- Router: one wave per token, top-2 experts + weights ----------------
__global__ void router_kernel(const float* __restrict__ x,
                              const float* __restrict__ rw,
                              const float* __restrict__ rb,
                              int* __restrict__ tk_e,
                              float* __restrict__ tk_w) {
    int t = blockIdx.x * 4 + (threadIdx.x >> 6);
    int lane = threadIdx.x & 63;
    float acc[E_N];
#pragma unroll
    for (int e = 0; e < E_N; ++e) acc[e] = 0.f;
    const float* xr = x + (size_t)t * D_M;
    for (int d = lane; d < D_M; d += 64) {
        float xv = xr[d];
        const float* r = rw + d * E_N;
#pragma unroll
        for (int e = 0; e < E_N; ++e) acc[e] += xv * r[e];
    }
#pragma unroll
    for (int off = 32; off > 0; off >>= 1) {
#pragma unroll
        for (int e = 0; e < E_N; ++e) acc[e] += __shfl_down(acc[e], off);
    }
    if (lane == 0) {
        float la[E_N];
#pragma unroll
        for (int e = 0; e < E_N; ++e) la[e] = acc[e] + rb[e];
        int e0 = 0; float l0 = la[0];
#pragma unroll
        for (int e = 1; e < E_N; ++e) { if (la[e] > l0) { l0 = la[e]; e0 = e; } }
        int e1 = -1; float l1 = -3.0e38f;
#pragma unroll
        for (int e = 0; e < E_N; ++e) { if (e != e0 && la[e] > l1) { l1 = la[e]; e1 = e; } }
        // top2 softmax renormalized == sigmoid of logit gap
        float w0 = 1.f / (1.f + expf(l1 - l0));
        tk_e[2 * t]     = e0;
        tk_e[2 * t + 1] = e1;
        tk_w[2 * t]     = w0;
        tk_w[2 * t + 1] = 1.f - w0;
    }
}

// ---------------- Per-chunk expert histogram (chunk = 64 assignments = 1 wave) ----------------
__global__ void hist_kernel(const int* __restrict__ tk_e, int* __restrict__ hist) {
    int a = blockIdx.x * 256 + threadIdx.x;
    int lane = threadIdx.x & 63;
    int chunk = a >> 6;
    int e = tk_e[a];
#pragma unroll
    for (int ee = 0; ee < E_N; ++ee) {
        unsigned long long b = __ballot(e == ee);
        if (lane == ee) hist[chunk * E_N + ee] = (int)__popcll(b);
    }
}

// ---------------- Exclusive prefix over chunks, per expert ----------------
__global__ void scan_kernel(const int* __restrict__ hist, int* __restrict__ cpre) {
    int e = threadIdx.x;
    if (e < E_N) {
        int run = 0;
#pragma unroll 8
        for (int c = 0; c < NCHUNK; ++c) {
            cpre[c * E_N + e] = run;
            run += hist[c * E_N + e];
        }
    }
}

__global__ void init_slots_kernel(int* __restrict__ slot_token) {
    int i = blockIdx.x * 256 + threadIdx.x;
    if (i < E_N * CAP) slot_token[i] = -1;
}

// ---------------- Rank within expert (stable order), capacity drop, slot maps ----------------
__global__ void slot_kernel(const int* __restrict__ tk_e, const int* __restrict__ cpre,
                            int* __restrict__ a_slot, int* __restrict__ slot_token) {
    int a = blockIdx.x * 256 + threadIdx.x;
    int lane = threadIdx.x & 63;
    int chunk = a >> 6;
    int e = tk_e[a];
    unsigned long long mymask = 0;
#pragma unroll
    for (int ee = 0; ee < E_N; ++ee) {
        unsigned long long b = __ballot(e == ee);
        if (e == ee) mymask = b;
    }
    int rank = cpre[chunk * E_N + e] + (int)__popcll(mymask & ((1ull << lane) - 1ull));
    int slot = (rank < CAP) ? e * CAP + rank : -1;
    a_slot[a] = slot;
    if (slot >= 0) slot_token[slot] = a >> 1;
}

// ---------------- Gather tokens into [E*CAP, D] bf16 buffer (zeros for empty slots) ----------------
__global__ void dispatch_kernel(const float* __restrict__ x, const int* __restrict__ slot_token,
                                unsigned short* __restrict__ xbuf) {
    int row = blockIdx.x;
    int tok = slot_token[row];
    int c = threadIdx.x * 4;
    float4 v = {0.f, 0.f, 0.f, 0.f};
    if (tok >= 0) v = *(const float4*)(x + (size_t)tok * D_M + c);
    union { unsigned short s[4]; uint2 u; } o;
    o.s[0] = f2bf(v.x); o.s[1] = f2bf(v.y); o.s[2] = f2bf(v.z); o.s[3] = f2bf(v.w);
    *(uint2*)(xbuf + (size_t)row * D_M + c) = o.u;
}

// ---------------- Weight convert + transpose: [e][R][C] f32 -> [e][C][R] bf16 ----------------
__global__ void wconv_kernel(const float* __restrict__ in, unsigned short* __restrict__ out,
                             int R, int C) {
    __shared__ float tile[32][33];
    int e = blockIdx.z;
    int c0 = blockIdx.x * 32;
    int r0 = blockIdx.y * 32;
    const float* ine = in + (size_t)e * R * C;
    unsigned short* oute = out + (size_t)e * R * C;
    int tr = threadIdx.x >> 3;
    int tc = (threadIdx.x & 7) * 4;
    float4 v = *(const float4*)(ine + (size_t)(r0 + tr) * C + c0 + tc);
    tile[tr][tc + 0] = v.x; tile[tr][tc + 1] = v.y;
    tile[tr][tc + 2] = v.z; tile[tr][tc + 3] = v.w;
    __syncthreads();
    int oc = threadIdx.x >> 3;          // local out-row (= in col)
    int orr = (threadIdx.x & 7) * 4;    // local out-col (= in row)
    union { unsigned short s[4]; uint2 u; } o;
#pragma unroll
    for (int j = 0; j < 4; ++j) o.s[j] = f2bf(tile[orr + j][oc]);
    *(uint2*)(oute + (size_t)(c0 + oc) * R + r0 + orr) = o.u;
}

// ---------------- bf16 MFMA GEMM (m97 structure + XOR-swizzled LDS) ----------------
// C[e] = epi(A[e][M,K] @ B[e][N,K]^T + bias[e])
// 128x128 tile, BK=64, 4 waves (2x2), each wave 64x64 via 4x4 of 16x16x32 MFMA.
// global_load_lds width=16 staging; LDS dest order is hardware-fixed (base+lane*16),
// so the XOR swizzle is applied on the GLOBAL SOURCE side: LDS slot (row r, chunk k)
// holds global chunk k^(r&7). Fragment ds_read_b128 then hits bank-group
// (kc^(m&7))*4 -> all 8 groups per 8-lane phase -> conflict-free (was 16-way).
// MFMA operands swapped (bf, af) -> D transposed: lane holds row m=lane&15,
// cols n = quad*4+reg -> 8B packed stores. XCD swizzle: e = id%8.
template <int EPI>
__global__ __launch_bounds__(256) void gemm_kernel(
    const unsigned short* __restrict__ A,
    const unsigned short* __restrict__ B,
    const float* __restrict__ bias,
    unsigned short* __restrict__ C,
    int M, int N, int K, int nt) {
    __shared__ __align__(16) unsigned short As[128 * 64];
    __shared__ __align__(16) unsigned short Bs[128 * 64];
    int id = blockIdx.x;
    int e = id & 7;
    int local = id >> 3;
    int m0 = (local / nt) * 128;
    int n0 = (local % nt) * 128;
    const unsigned short* Ae = A + (size_t)e * M * K + (size_t)m0 * K;
    const unsigned short* Be = B + (size_t)e * N * K + (size_t)n0 * K;
    int tid = threadIdx.x;
    int lane = tid & 63;
    int wave = tid >> 6;
    int wm = (wave >> 1) * 64;
    int wn = (wave & 1) * 64;
    int l15 = lane & 15;
    int l4 = lane >> 4;
    // staging: LDS slot for this thread is row p*32 + tid/8, lds-chunk tid&7.
    // It must hold global chunk (tid&7) ^ (row&7); row&7 == (tid>>3)&7.
    int srow = tid >> 3;                         // 0..31
    int kg = (tid & 7) ^ (srow & 7);             // swizzled global chunk
    int scol = kg * 8;                           // global column offset (elements)
    int sx = l15 & 7;                            // fragment-read xor term (m&7)

    floatx4 acc[4][4];
#pragma unroll
    for (int i = 0; i < 4; ++i)
#pragma unroll
        for (int j = 0; j < 4; ++j) acc[i][j] = (floatx4){0.f, 0.f, 0.f, 0.f};

    for (int kt = 0; kt < K; kt += 64) {
        __syncthreads();   // prior iter's LDS reads must finish before overwrite
#pragma unroll
        for (int p = 0; p < 4; ++p) {
            async16(Ae + (size_t)(p * 32 + srow) * K + kt + scol, As + p * 2048 + tid * 8);
            async16(Be + (size_t)(p * 32 + srow) * K + kt + scol, Bs + p * 2048 + tid * 8);
        }
        __syncthreads();   // drains vmcnt: staging visible
#pragma unroll
        for (int ks = 0; ks < 2; ++ks) {
            shortx8 af[4], bf[4];
            int kc = ks * 4 + l4;
            int kcx = (kc ^ sx) * 8;             // swizzled LDS chunk offset
#pragma unroll
            for (int i = 0; i < 4; ++i) {
                af[i] = *(const shortx8*)(As + (wm + i * 16 + l15) * 64 + kcx);
                bf[i] = *(const shortx8*)(Bs + (wn + i * 16 + l15) * 64 + kcx);
            }
#pragma unroll
            for (int i = 0; i < 4; ++i)
#pragma unroll
                for (int j = 0; j < 4; ++j)
                    acc[i][j] = __builtin_amdgcn_mfma_f32_16x16x32_bf16(bf[j], af[i], acc[i][j], 0, 0, 0);
        }
    }

    // Epilogue: swapped-operand D layout: lane row m = lane&15, cols n = l4*4 + reg
#pragma unroll
    for (int i = 0; i < 4; ++i) {
        int row = m0 + wm + i * 16 + l15;
#pragma unroll
        for (int j = 0; j < 4; ++j) {
            int ncol = n0 + wn + j * 16 + l4 * 4;
            float4 bv = *(const float4*)(bias + (size_t)e * N + ncol);
            union { unsigned short s[4]; uint2 u; } o;
#pragma unroll
            for (int r = 0; r < 4; ++r) {
                float v = acc[i][j][r] + ((const float*)&bv)[r];
                if (EPI == 0) v = 0.5f * v * (1.0f + erff(v * 0.70710678118654752f));
                o.s[r] = f2bf(v);
            }
            *(uint2*)(C + ((size_t)e * M + row) * N + ncol) = o.u;
        }
    }
}

// ---------------- Combine: out[t] = sum_k w_k * eo[slot_k] ----------------
__global__ void combine_kernel(const unsigned short* __restrict__ eo,
                               const int* __restrict__ a_slot,
                               const float* __restrict__ tk_w,
                               float* __restrict__ out) {
    int t = blockIdx.x;
    int c = threadIdx.x * 4;
    int s0 = a_slot[2 * t], s1 = a_slot[2 * t + 1];
    float w0 = tk_w[2 * t], w1 = tk_w[2 * t + 1];
    float o0 = 0.f, o1 = 0.f, o2 = 0.f, o3 = 0.f;
    if (s0 >= 0) {
        union { unsigned short s[4]; uint2 u; } v;
        v.u = *(const uint2*)(eo + (size_t)s0 * D_M + c);
        o0 += w0 * bf2f(v.s[0]); o1 += w0 * bf2f(v.s[1]);
        o2 += w0 * bf2f(v.s[2]); o3 += w0 * bf2f(v.s[3]);
    }
    if (s1 >= 0) {
        union { unsigned short s[4]; uint2 u; } v;
        v.u = *(const uint2*)(eo + (size_t)s1 * D_M + c);
        o0 += w1 * bf2f(v.s[0]); o1 += w1 * bf2f(v.s[1]);
        o2 += w1 * bf2f(v.s[2]); o3 += w1 * bf2f(v.s[3]);
    }
    float4 o = {o0, o1, o2, o3};
    *(float4*)(out + (size_t)t * D_M + c) = o;
}

extern "C" void kernel_launch(void* const* d_in, const int* in_sizes, int n_in,
                              void* d_out, int out_size, void* d_ws, size_t ws_size,
                              hipStream_t stream) {
    const float* x  = (const float*)d_in[0];
    const float* rw = (const float*)d_in[1];
    const float* rb = (const float*)d_in[2];
    const float* w1 = (const float*)d_in[3];
    const float* b1 = (const float*)d_in[4];
    const float* w2 = (const float*)d_in[5];
    const float* b2 = (const float*)d_in[6];
    float* out = (float*)d_out;

    char* ws = (char*)d_ws;
    size_t off = 0;
    auto alloc = [&](size_t bytes) -> char* {
        char* p = ws + off;
        off += (bytes + 255) & ~(size_t)255;
        return p;
    };
    unsigned short* w1t  = (unsigned short*)alloc((size_t)E_N * D_M * F_F * 2);  // [E][F][D] bf16
    unsigned short* w2t  = (unsigned short*)alloc((size_t)E_N * D_M * F_F * 2);  // [E][D][F] bf16
    unsigned short* xbuf = (unsigned short*)alloc((size_t)E_N * CAP * D_M * 2);  // [E*CAP][D] bf16
    unsigned short* h    = (unsigned short*)alloc((size_t)E_N * CAP * F_F * 2);  // [E*CAP][F] bf16
    unsigned short* eo   = (unsigned short*)alloc((size_t)E_N * CAP * D_M * 2);  // [E*CAP][D] bf16
    int*   tk_e       = (int*)alloc((size_t)A_N * 4);
    float* tk_w       = (float*)alloc((size_t)A_N * 4);
    int*   hist       = (int*)alloc((size_t)NCHUNK * E_N * 4);
    int*   cpre       = (int*)alloc((size_t)NCHUNK * E_N * 4);
    int*   a_slot     = (int*)alloc((size_t)A_N * 4);
    int*   slot_token = (int*)alloc((size_t)E_N * CAP * 4);
    if (off > ws_size) {
        fprintf(stderr, "kernel_launch: workspace too small: need %zu, have %zu\n", off, ws_size);
        return;
    }

    // weight bf16 transpose-convert (independent of routing)
    wconv_kernel<<<dim3(F_F / 32, D_M / 32, E_N), 256, 0, stream>>>(w1, w1t, D_M, F_F);
    wconv_kernel<<<dim3(D_M / 32, F_F / 32, E_N), 256, 0, stream>>>(w2, w2t, F_F, D_M);
    // routing pipeline
    router_kernel<<<T_TOK / 4, 256, 0, stream>>>(x, rw, rb, tk_e, tk_w);
    hist_kernel<<<A_N / 256, 256, 0, stream>>>(tk_e, hist);
    scan_kernel<<<1, 64, 0, stream>>>(hist, cpre);
    init_slots_kernel<<<(E_N * CAP + 255) / 256, 256, 0, stream>>>(slot_token);
    slot_kernel<<<A_N / 256, 256, 0, stream>>>(tk_e, cpre, a_slot, slot_token);
    dispatch_kernel<<<E_N * CAP, 256, 0, stream>>>(x, slot_token, xbuf);
    // expert FFN (1D grids: E * mt * nt blocks, XCD swizzle inside)
    gemm_kernel<0><<<E_N * (CAP / 128) * (F_F / 128), 256, 0, stream>>>(
        xbuf, w1t, b1, h, CAP, F_F, D_M, F_F / 128);
    gemm_kernel<1><<<E_N * (CAP / 128) * (D_M / 128), 256, 0, stream>>>(
        h, w2t, b2, eo, CAP, D_M, F_F, D_M / 128);
    // weighted combine
    combine_kernel<<<T_TOK, 256, 0, stream>>>(eo, a_slot, tk_w, out);
}

// Round 4
// 425.733 us; speedup vs baseline: 2.7900x; 1.1906x over previous
//
#include <hip/hip_runtime.h>
#include <cstdio>
#include <cstdint>
#include <cstddef>

// Problem constants (B=4, S=2048, D=1024, F=2048, E=8, K=2, CF=1.25)
#define T_TOK 8192
#define E_N 8
#define D_M 1024
#define F_F 2048
#define A_N (T_TOK * 2)      // 16384 assignments
#define CAP 2560             // ceil(1.25 * 16384 / 8)
#define NCHUNK (A_N / 64)    // 256 chunks of 64 assignments

typedef __attribute__((ext_vector_type(4))) float floatx4;
typedef __attribute__((ext_vector_type(8))) short shortx8;

__device__ __forceinline__ unsigned short f2bf(float f) {
    union { float f; unsigned int u; } v; v.f = f;
    unsigned int u = v.u;
    u += 0x7fffu + ((u >> 16) & 1u);   // round-to-nearest-even
    return (unsigned short)(u >> 16);
}
__device__ __forceinline__ float bf2f(unsigned short h) {
    union { unsigned int u; float f; } v; v.u = ((unsigned int)h) << 16;
    return v.f;
}

// async global->LDS, 16B per lane (dest = wave-uniform base + lane*16)
__device__ __forceinline__ void async16(const unsigned short* g, unsigned short* l) {
    __builtin_amdgcn_global_load_lds(
        (const __attribute__((address_space(1))) unsigned int*)(g),
        (__attribute__((address_space(3))) unsigned int*)(l),
        16, 0, 0);
}

// ---------------- Router: one wave per token, top-2 experts + weights ----------------
__global__ void router_kernel(const float* __restrict__ x,
                              const float* __restrict__ rw,
                              const float* __restrict__ rb,
                              int* __restrict__ tk_e,
                              float* __restrict__ tk_w) {
    int t = blockIdx.x * 4 + (threadIdx.x >> 6);
    int lane = threadIdx.x & 63;
    float acc[E_N];
#pragma unroll
    for (int e = 0; e < E_N; ++e) acc[e] = 0.f;
    const float* xr = x + (size_t)t * D_M;
    for (int d = lane; d < D_M; d += 64) {
        float xv = xr[d];
        const float* r = rw + d * E_N;
#pragma unroll
        for (int e = 0; e < E_N; ++e) acc[e] += xv * r[e];
    }
#pragma unroll
    for (int off = 32; off > 0; off >>= 1) {
#pragma unroll
        for (int e = 0; e < E_N; ++e) acc[e] += __shfl_down(acc[e], off);
    }
    if (lane == 0) {
        float la[E_N];
#pragma unroll
        for (int e = 0; e < E_N; ++e) la[e] = acc[e] + rb[e];
        int e0 = 0; float l0 = la[0];
#pragma unroll
        for (int e = 1; e < E_N; ++e) { if (la[e] > l0) { l0 = la[e]; e0 = e; } }
        int e1 = -1; float l1 = -3.0e38f;
#pragma unroll
        for (int e = 0; e < E_N; ++e) { if (e != e0 && la[e] > l1) { l1 = la[e]; e1 = e; } }
        // top2 softmax renormalized == sigmoid of logit gap
        float w0 = 1.f / (1.f + expf(l1 - l0));
        tk_e[2 * t]     = e0;
        tk_e[2 * t + 1] = e1;
        tk_w[2 * t]     = w0;
        tk_w[2 * t + 1] = 1.f - w0;
    }
}

// ------ Per-chunk expert histogram + slot_token init (fused; grid 80x256 = 20480) ------
__global__ void hist_init_kernel(const int* __restrict__ tk_e, int* __restrict__ hist,
                                 int* __restrict__ slot_token) {
    int i = blockIdx.x * 256 + threadIdx.x;
    if (i < E_N * CAP) slot_token[i] = -1;
    if (i < A_N) {   // blocks 0..63 fully active, 64..79 uniformly skip
        int lane = threadIdx.x & 63;
        int chunk = i >> 6;
        int e = tk_e[i];
#pragma unroll
        for (int ee = 0; ee < E_N; ++ee) {
            unsigned long long b = __ballot(e == ee);
            if (lane == ee) hist[chunk * E_N + ee] = (int)__popcll(b);
        }
    }
}

// ------ Parallel exclusive prefix over 256 chunks, per expert: wave e scans expert e ------
__global__ void scan_kernel(const int* __restrict__ hist, int* __restrict__ cpre) {
    int e = threadIdx.x >> 6;    // 8 waves, one per expert
    int lane = threadIdx.x & 63; // lane handles chunks 4*lane .. 4*lane+3
    int h0 = hist[(4 * lane + 0) * E_N + e];
    int h1 = hist[(4 * lane + 1) * E_N + e];
    int h2 = hist[(4 * lane + 2) * E_N + e];
    int h3 = hist[(4 * lane + 3) * E_N + e];
    int t = h0 + h1 + h2 + h3;
    int inc = t;
#pragma unroll
    for (int off = 1; off < 64; off <<= 1) {
        int v = __shfl_up(inc, off);
        if (lane >= off) inc += v;
    }
    int base = inc - t;   // exclusive prefix of lane totals
    cpre[(4 * lane + 0) * E_N + e] = base;
    cpre[(4 * lane + 1) * E_N + e] = base + h0;
    cpre[(4 * lane + 2) * E_N + e] = base + h0 + h1;
    cpre[(4 * lane + 3) * E_N + e] = base + h0 + h1 + h2;
}

// ---------------- Rank within expert (stable order), capacity drop, slot maps ----------------
__global__ void slot_kernel(const int* __restrict__ tk_e, const int* __restrict__ cpre,
                            int* __restrict__ a_slot, int* __restrict__ slot_token) {
    int a = blockIdx.x * 256 + threadIdx.x;
    int lane = threadIdx.x & 63;
    int chunk = a >> 6;
    int e = tk_e[a];
    unsigned long long mymask = 0;
#pragma unroll
    for (int ee = 0; ee < E_N; ++ee) {
        unsigned long long b = __ballot(e == ee);
        if (e == ee) mymask = b;
    }
    int rank = cpre[chunk * E_N + e] + (int)__popcll(mymask & ((1ull << lane) - 1ull));
    int slot = (rank < CAP) ? e * CAP + rank : -1;
    a_slot[a] = slot;
    if (slot >= 0) slot_token[slot] = a >> 1;
}

// ------ Gather tokens into [E*CAP, D] bf16 buffer (zeros for empty slots); 16B/lane ------
__global__ void dispatch_kernel(const float* __restrict__ x, const int* __restrict__ slot_token,
                                unsigned short* __restrict__ xbuf) {
    int r = blockIdx.x * 2 + (threadIdx.x >> 7);
    int c = (threadIdx.x & 127) * 8;
    int tok = slot_token[r];
    float4 v0 = {0.f, 0.f, 0.f, 0.f}, v1 = {0.f, 0.f, 0.f, 0.f};
    if (tok >= 0) {
        const float* p = x + (size_t)tok * D_M + c;
        v0 = *(const float4*)p;
        v1 = *(const float4*)(p + 4);
    }
    union { unsigned short s[8]; uint4 u; } o;
    o.s[0] = f2bf(v0.x); o.s[1] = f2bf(v0.y); o.s[2] = f2bf(v0.z); o.s[3] = f2bf(v0.w);
    o.s[4] = f2bf(v1.x); o.s[5] = f2bf(v1.y); o.s[6] = f2bf(v1.z); o.s[7] = f2bf(v1.w);
    *(uint4*)(xbuf + (size_t)r * D_M + c) = o.u;
}

// ------ Weight convert+transpose for BOTH w1 and w2 in one launch ------
// w1: [e][D][F] f32 -> w1t [e][F][D] bf16 (R=D,C=F); w2: [e][F][D] -> w2t [e][D][F] (R=F,C=D)
__global__ void wconv2_kernel(const float* __restrict__ w1, const float* __restrict__ w2,
                              unsigned short* __restrict__ w1t, unsigned short* __restrict__ w2t) {
    __shared__ float tile[32][33];
    int id = blockIdx.x;
    bool second = id >= 16384;
    const float* in = second ? w2 : w1;
    unsigned short* outp = second ? w2t : w1t;
    int R = second ? F_F : D_M;
    int C = second ? D_M : F_F;
    int local = second ? id - 16384 : id;
    int e = local >> 11;            // 2048 blocks per expert either way
    int rem = local & 2047;
    int nrt = R >> 5;
    int rt = rem % nrt;
    int ct = rem / nrt;
    int r0 = rt * 32, c0 = ct * 32;
    const float* ine = in + (size_t)e * D_M * F_F;
    unsigned short* oute = outp + (size_t)e * D_M * F_F;
    int tr = threadIdx.x >> 3;
    int tc = (threadIdx.x & 7) * 4;
    float4 v = *(const float4*)(ine + (size_t)(r0 + tr) * C + c0 + tc);
    tile[tr][tc + 0] = v.x; tile[tr][tc + 1] = v.y;
    tile[tr][tc + 2] = v.z; tile[tr][tc + 3] = v.w;
    __syncthreads();
    int oc = threadIdx.x >> 3;          // local out-row (= in col)
    int orr = (threadIdx.x & 7) * 4;    // local out-col (= in row)
    union { unsigned short s[4]; uint2 u; } o;
#pragma unroll
    for (int j = 0; j < 4; ++j) o.s[j] = f2bf(tile[orr + j][oc]);
    *(uint2*)(oute + (size_t)(c0 + oc) * R + r0 + orr) = o.u;
}

// ---------------- bf16 MFMA GEMM (register-prefetch pipeline + XOR-swizzled LDS) ----------
// C[e] = epi(A[e][M,K] @ B[e][N,K]^T + bias[e])
// 128x128 tile, BK=64, 4 waves (2x2), each wave 64x64 via 4x4 of 16x16x32 MFMA.
// Pipeline per K-iter: B1(drain DMA) -> ds_read ALL frags to regs -> B2(reads done)
// -> issue next tile's DMA -> MFMA on regs (overlaps DMA in flight).
// XOR swizzle on the GLOBAL SOURCE side (LDS dest order is HW-fixed): LDS slot
// (row r, chunk k) holds global chunk k^(r&7) -> frag ds_read_b128 conflict-free.
// MFMA operands swapped (bf,af) -> D transposed: 8B packed C stores.
template <int EPI>
__global__ __launch_bounds__(256, 3) void gemm_kernel(
    const unsigned short* __restrict__ A,
    const unsigned short* __restrict__ B,
    const float* __restrict__ bias,
    unsigned short* __restrict__ C,
    int M, int N, int K, int nt) {
    __shared__ __align__(16) unsigned short As[128 * 64];
    __shared__ __align__(16) unsigned short Bs[128 * 64];
    int id = blockIdx.x;
    int e = id & 7;
    int local = id >> 3;
    int m0 = (local / nt) * 128;
    int n0 = (local % nt) * 128;
    const unsigned short* Ae = A + (size_t)e * M * K + (size_t)m0 * K;
    const unsigned short* Be = B + (size_t)e * N * K + (size_t)n0 * K;
    int tid = threadIdx.x;
    int lane = tid & 63;
    int wave = tid >> 6;
    int wm = (wave >> 1) * 64;
    int wn = (wave & 1) * 64;
    int l15 = lane & 15;
    int l4 = lane >> 4;
    int srow = tid >> 3;                         // staging row 0..31 (per 32-row group)
    int kg = (tid & 7) ^ (srow & 7);             // swizzled global chunk
    int scol = kg * 8;                           // global column offset (elements)
    int sx = l15 & 7;                            // fragment-read xor term (m&7)

    floatx4 acc[4][4];
#pragma unroll
    for (int i = 0; i < 4; ++i)
#pragma unroll
        for (int j = 0; j < 4; ++j) acc[i][j] = (floatx4){0.f, 0.f, 0.f, 0.f};

    // prologue: stage tile 0
#pragma unroll
    for (int p = 0; p < 4; ++p) {
        async16(Ae + (size_t)(p * 32 + srow) * K + scol, As + p * 2048 + tid * 8);
        async16(Be + (size_t)(p * 32 + srow) * K + scol, Bs + p * 2048 + tid * 8);
    }

    for (int kt = 0; kt < K; kt += 64) {
        __syncthreads();   // drains vmcnt(0): this tile's DMA visible
        shortx8 af[2][4], bf[2][4];
#pragma unroll
        for (int ks = 0; ks < 2; ++ks) {
            int kcx = ((ks * 4 + l4) ^ sx) * 8;
#pragma unroll
            for (int i = 0; i < 4; ++i) {
                af[ks][i] = *(const shortx8*)(As + (wm + i * 16 + l15) * 64 + kcx);
                bf[ks][i] = *(const shortx8*)(Bs + (wn + i * 16 + l15) * 64 + kcx);
            }
        }
        __syncthreads();   // all waves finished reading LDS (lgkm drained)
        if (kt + 64 < K) { // issue next tile's DMA; MFMA below overlaps it
#pragma unroll
            for (int p = 0; p < 4; ++p) {
                async16(Ae + (size_t)(p * 32 + srow) * K + kt + 64 + scol, As + p * 2048 + tid * 8);
                async16(Be + (size_t)(p * 32 + srow) * K + kt + 64 + scol, Bs + p * 2048 + tid * 8);
            }
        }
#pragma unroll
        for (int ks = 0; ks < 2; ++ks)
#pragma unroll
            for (int i = 0; i < 4; ++i)
#pragma unroll
                for (int j = 0; j < 4; ++j)
                    acc[i][j] = __builtin_amdgcn_mfma_f32_16x16x32_bf16(bf[ks][j], af[ks][i], acc[i][j], 0, 0, 0);
    }

    // Epilogue: swapped-operand D layout: lane row m = lane&15, cols n = l4*4 + reg
#pragma unroll
    for (int i = 0; i < 4; ++i) {
        int row = m0 + wm + i * 16 + l15;
#pragma unroll
        for (int j = 0; j < 4; ++j) {
            int ncol = n0 + wn + j * 16 + l4 * 4;
            float4 bv = *(const float4*)(bias + (size_t)e * N + ncol);
            union { unsigned short s[4]; uint2 u; } o;
#pragma unroll
            for (int r = 0; r < 4; ++r) {
                float v = acc[i][j][r] + ((const float*)&bv)[r];
                if (EPI == 0) v = 0.5f * v * (1.0f + erff(v * 0.70710678118654752f));
                o.s[r] = f2bf(v);
            }
            *(uint2*)(C + ((size_t)e * M + row) * N + ncol) = o.u;
        }
    }
}

// ---------------- Combine: out[t] = sum_k w_k * eo[slot_k]; 16B reads, 32B writes ----------------
__global__ void combine_kernel(const unsigned short* __restrict__ eo,
                               const int* __restrict__ a_slot,
                               const float* __restrict__ tk_w,
                               float* __restrict__ out) {
    int t = blockIdx.x * 2 + (threadIdx.x >> 7);
    int c = (threadIdx.x & 127) * 8;
    int s0 = a_slot[2 * t], s1 = a_slot[2 * t + 1];
    float w0 = tk_w[2 * t], w1 = tk_w[2 * t + 1];
    float o[8];
#pragma unroll
    for (int k = 0; k < 8; ++k) o[k] = 0.f;
    if (s0 >= 0) {
        union { unsigned short s[8]; uint4 u; } v;
        v.u = *(const uint4*)(eo + (size_t)s0 * D_M + c);
#pragma unroll
        for (int k = 0; k < 8; ++k) o[k] += w0 * bf2f(v.s[k]);
    }
    if (s1 >= 0) {
        union { unsigned short s[8]; uint4 u; } v;
        v.u = *(const uint4*)(eo + (size_t)s1 * D_M + c);
#pragma unroll
        for (int k = 0; k < 8; ++k) o[k] += w1 * bf2f(v.s[k]);
    }
    float* po = out + (size_t)t * D_M + c;
    *(float4*)po = (float4){o[0], o[1], o[2], o[3]};
    *(float4*)(po + 4) = (float4){o[4], o[5], o[6], o[7]};
}

extern "C" void kernel_launch(void* const* d_in, const int* in_sizes, int n_in,
                              void* d_out, int out_size, void* d_ws, size_t ws_size,
                              hipStream_t stream) {
    const float* x  = (const float*)d_in[0];
    const float* rw = (const float*)d_in[1];
    const float* rb = (const float*)d_in[2];
    const float* w1 = (const float*)d_in[3];
    const float* b1 = (const float*)d_in[4];
    const float* w2 = (const float*)d_in[5];
    const float* b2 = (const float*)d_in[6];
    float* out = (float*)d_out;

    char* ws = (char*)d_ws;
    size_t off = 0;
    auto alloc = [&](size_t bytes) -> char* {
        char* p = ws + off;
        off += (bytes + 255) & ~(size_t)255;
        return p;
    };
    unsigned short* w1t  = (unsigned short*)alloc((size_t)E_N * D_M * F_F * 2);  // [E][F][D] bf16
    unsigned short* w2t  = (unsigned short*)alloc((size_t)E_N * D_M * F_F * 2);  // [E][D][F] bf16
    unsigned short* xbuf = (unsigned short*)alloc((size_t)E_N * CAP * D_M * 2);  // [E*CAP][D] bf16
    unsigned short* h    = (unsigned short*)alloc((size_t)E_N * CAP * F_F * 2);  // [E*CAP][F] bf16
    unsigned short* eo   = (unsigned short*)alloc((size_t)E_N * CAP * D_M * 2);  // [E*CAP][D] bf16
    int*   tk_e       = (int*)alloc((size_t)A_N * 4);
    float* tk_w       = (float*)alloc((size_t)A_N * 4);
    int*   hist       = (int*)alloc((size_t)NCHUNK * E_N * 4);
    int*   cpre       = (int*)alloc((size_t)NCHUNK * E_N * 4);
    int*   a_slot     = (int*)alloc((size_t)A_N * 4);
    int*   slot_token = (int*)alloc((size_t)E_N * CAP * 4);
    if (off > ws_size) {
        fprintf(stderr, "kernel_launch: workspace too small: need %zu, have %zu\n", off, ws_size);
        return;
    }

    // weight bf16 transpose-convert (independent of routing; single launch for w1+w2)
    wconv2_kernel<<<32768, 256, 0, stream>>>(w1, w2, w1t, w2t);
    // routing pipeline
    router_kernel<<<T_TOK / 4, 256, 0, stream>>>(x, rw, rb, tk_e, tk_w);
    hist_init_kernel<<<80, 256, 0, stream>>>(tk_e, hist, slot_token);
    scan_kernel<<<1, 512, 0, stream>>>(hist, cpre);
    slot_kernel<<<A_N / 256, 256, 0, stream>>>(tk_e, cpre, a_slot, slot_token);
    dispatch_kernel<<<E_N * CAP / 2, 256, 0, stream>>>(x, slot_token, xbuf);
    // expert FFN (1D grids: E * mt * nt blocks, XCD swizzle inside)
    gemm_kernel<0><<<E_N * (CAP / 128) * (F_F / 128), 256, 0, stream>>>(
        xbuf, w1t, b1, h, CAP, F_F, D_M, F_F / 128);
    gemm_kernel<1><<<E_N * (CAP / 128) * (D_M / 128), 256, 0, stream>>>(
        h, w2t, b2, eo, CAP, D_M, F_F, D_M / 128);
    // weighted combine
    combine_kernel<<<T_TOK / 2, 256, 0, stream>>>(eo, a_slot, tk_w, out);
}